// Round 14
// baseline (818.464 us; speedup 1.0000x reference)
//
#include <hip/hip_runtime.h>

// MHA forward: B=2, S=4096, D=768, H=12, Dh=64.
// cvt(weights->bf16) -> gemm_qkv (A fp32-staged, B bf16) -> flash attention
// (swapped QK^T 32x32, KVBLK=64, XCD-stream swizzle, 3-buffer cross-tile
// software pipeline: QK(t+1) interleaved with softmax+PV(t)) -> gemm_out.

typedef __attribute__((ext_vector_type(4))) float f32x4;
typedef __attribute__((ext_vector_type(16))) float f32x16;
typedef __attribute__((ext_vector_type(8))) __bf16 bf16x8;
typedef __attribute__((ext_vector_type(2))) int i32x2;
typedef __attribute__((ext_vector_type(4))) unsigned u32x4;
using u16 = unsigned short;
using u32 = unsigned;

__device__ __forceinline__ u16 f2bf(float x) {
  __bf16 h = (__bf16)x;
  return __builtin_bit_cast(u16, h);
}
__device__ __forceinline__ u32 pk2(float lo, float hi) {  // v_cvt_pk_bf16_f32 (RNE)
  u32 r;
  asm("v_cvt_pk_bf16_f32 %0, %1, %2" : "=v"(r) : "v"(lo), "v"(hi));
  return r;
}
__device__ __forceinline__ void gload16(u16* ldsDst, const u16* gSrc) {
  __builtin_amdgcn_global_load_lds(
      (const __attribute__((address_space(1))) void*)gSrc,
      (__attribute__((address_space(3))) void*)ldsDst, 16, 0, 0);
}
__device__ __forceinline__ f32x4 mfma16(bf16x8 a, bf16x8 b, f32x4 c) {
  return __builtin_amdgcn_mfma_f32_16x16x32_bf16(a, b, c, 0, 0, 0);
}
__device__ __forceinline__ f32x16 mfma32(bf16x8 a, bf16x8 b, f32x16 c) {
  return __builtin_amdgcn_mfma_f32_32x32x16_bf16(a, b, c, 0, 0, 0);
}
__device__ __forceinline__ bf16x8 ld8(const u16* p) { return *(const bf16x8*)p; }

// ---------------------------------------------------------------- cvt (weights only)
__global__ void cvt_hi(const float4* __restrict__ in0, u16* o0,
                       const float4* __restrict__ in1, u16* o1,
                       const float4* __restrict__ in2, u16* o2,
                       const float4* __restrict__ in3, u16* o3, int n4) {
  const float4* in = in0; u16* o = o0;
  if (blockIdx.y == 1) { in = in1; o = o1; }
  else if (blockIdx.y == 2) { in = in2; o = o2; }
  else if (blockIdx.y == 3) { in = in3; o = o3; }
  const int stride = gridDim.x * blockDim.x;
  for (int i = blockIdx.x * blockDim.x + threadIdx.x; i < n4; i += stride) {
    float4 x = in[i];
    *(ushort4*)&o[i * 4] = make_ushort4(f2bf(x.x), f2bf(x.y), f2bf(x.z), f2bf(x.w));
  }
}

// ---------------------------------------------------------------- QKV projection GEMM
// C = A * B^T + bias. A:[8192,768] fp32 (staged fp32, cvt on read), B bf16.
__global__ __launch_bounds__(256, 2) void gemm_qkv(
    const float* __restrict__ Aq, const float* __restrict__ Ak,
    const float* __restrict__ Av,
    const u16* __restrict__ wq, const u16* __restrict__ wk, const u16* __restrict__ wv,
    const float* __restrict__ bq, const float* __restrict__ bk,
    const float* __restrict__ bv,
    u16* __restrict__ oq, u16* __restrict__ ok, u16* __restrict__ ov,
    float qscale) {
  constexpr int K = 768;
  constexpr int BUF = 12288;  // u16 units: A 8192 (16KB fp32) | B 4096 (8KB bf16)
  __shared__ __align__(16) u16 lds[2 * BUF];
  const int z = blockIdx.z;
  const float* A = (z == 0) ? Aq : (z == 1) ? Ak : Av;
  const u16* Bh = (z == 0) ? wq : (z == 1) ? wk : wv;
  const float* bias = (z == 0) ? bq : (z == 1) ? bk : bv;
  u16* C = (z == 0) ? oq : (z == 1) ? ok : ov;
  const float scale = (z == 0) ? qscale : 1.f;
  const bool vmode = (z == 2);

  const int tid = threadIdx.x, lane = tid & 63, w = tid >> 6;
  const int wr = w >> 1, wc = w & 1;
  const int g = lane >> 4, la = lane & 15;
  const int m0 = blockIdx.x * 128, n0 = blockIdx.y * 128;

  f32x4 acc[4][4] = {};

  auto stage = [&](int buf, int kt) {
    const int k0 = kt * 32;
    u16* base = &lds[buf * BUF];
#pragma unroll
    for (int j = 0; j < 4; ++j) {
      const int i = w * 4 + j;
      const int r = i * 8 + (lane >> 3);
      const int c = (lane & 7) ^ ((lane >> 3) & 7);
      gload16(base + i * 512, (const u16*)(A + (size_t)(m0 + r) * K + k0 + c * 4));
    }
#pragma unroll
    for (int j = 0; j < 2; ++j) {
      const int t = w * 2 + j;
      const int s = t * 64 + lane;
      const int sr = s >> 3, ph = s & 7, ch = ph ^ (sr & 7);
      const int row = sr * 2 + (ch >> 2), c = ch & 3;
      gload16(base + 8192 + t * 512, Bh + (size_t)(n0 + row) * K + k0 + c * 8);
    }
  };
  auto rdfragA = [&](const float* baseF, int row, int gg) -> bf16x8 {
    const int x = row & 7;
    const f32x4 u = *(const f32x4*)(baseF + row * 32 + (((2 * gg) ^ x) << 2));
    const f32x4 v = *(const f32x4*)(baseF + row * 32 + (((2 * gg + 1) ^ x) << 2));
    u32x4 wq_ = {pk2(u[0], u[1]), pk2(u[2], u[3]), pk2(v[0], v[1]), pk2(v[2], v[3])};
    return __builtin_bit_cast(bf16x8, wq_);
  };
  auto rdfragB = [&](const u16* base, int row, int c) -> bf16x8 {
    const int sr = row >> 1;
    const int ph = (((row & 1) << 2) | c) ^ (sr & 7);
    return ld8(base + sr * 64 + ph * 8);
  };

  stage(0, 0);
  __syncthreads();
  constexpr int nk = K / 32;
  int cur = 0;
  for (int kt = 0; kt < nk; ++kt) {
    if (kt + 1 < nk) stage(cur ^ 1, kt + 1);
    const float* aF = (const float*)&lds[cur * BUF];
    const u16* bB = &lds[cur * BUF + 8192];
    bf16x8 aH[4], bH[4];
#pragma unroll
    for (int ni = 0; ni < 4; ++ni) bH[ni] = rdfragB(bB, wc * 64 + ni * 16 + la, g);
#pragma unroll
    for (int mi = 0; mi < 4; ++mi) aH[mi] = rdfragA(aF, wr * 64 + mi * 16 + la, g);
#pragma unroll
    for (int mi = 0; mi < 4; ++mi)
#pragma unroll
      for (int ni = 0; ni < 4; ++ni)
        acc[mi][ni] = mfma16(aH[mi], bH[ni], acc[mi][ni]);
    __syncthreads();
    cur ^= 1;
  }

#pragma unroll
  for (int mi = 0; mi < 4; ++mi) {
    const int mbase = m0 + wr * 64 + mi * 16 + g * 4;
#pragma unroll
    for (int ni = 0; ni < 4; ++ni) {
      const int n = n0 + wc * 64 + ni * 16 + la;
      const float bv_ = bias[n];
#pragma unroll
      for (int r = 0; r < 4; ++r) {
        const int m = mbase + r;
        const float y = (acc[mi][ni][r] + bv_) * scale;
        const int bb = m >> 12, s = m & 4095, hh = n >> 6, dh = n & 63;
        if (!vmode)
          C[((size_t)(bb * 12 + hh) * 4096 + s) * 64 + dh] = f2bf(y);
        else
          C[((size_t)(bb * 12 + hh) * 64 + dh) * 4096 + s] = f2bf(y);
      }
    }
  }
}

// ---------------------------------------------------------------- out-proj GEMM
__global__ __launch_bounds__(256, 2) void gemm_out(
    const u16* __restrict__ A, const u16* __restrict__ Bh,
    const float* __restrict__ bias, float* __restrict__ Cf) {
  constexpr int K = 768, N = 768;
  constexpr int BUF = 8192;
  __shared__ __align__(16) u16 lds[2 * BUF];
  const int tid = threadIdx.x, lane = tid & 63, w = tid >> 6;
  const int wr = w >> 1, wc = w & 1;
  const int g = lane >> 4, la = lane & 15;
  const int m0 = blockIdx.x * 128, n0 = blockIdx.y * 128;

  f32x4 acc[4][4] = {};

  auto stage = [&](int buf, int kt) {
    const int k0 = kt * 32;
#pragma unroll
    for (int j = 0; j < 2; ++j) {
      const int t = w * 2 + j;
      const int s = t * 64 + lane;
      const int sr = s >> 3, ph = s & 7, ch = ph ^ (sr & 7);
      const int row = sr * 2 + (ch >> 2), c = ch & 3;
      const int gofs = k0 + c * 8;
      u16* base = &lds[buf * BUF];
      gload16(base + t * 512, A + (size_t)(m0 + row) * K + gofs);
      gload16(base + 4096 + t * 512, Bh + (size_t)(n0 + row) * K + gofs);
    }
  };
  auto rdfrag = [&](const u16* base, int row, int c) -> bf16x8 {
    const int sr = row >> 1;
    const int ph = (((row & 1) << 2) | c) ^ (sr & 7);
    return ld8(base + sr * 64 + ph * 8);
  };

  stage(0, 0);
  __syncthreads();
  constexpr int nk = K / 32;
  int cur = 0;
  for (int kt = 0; kt < nk; ++kt) {
    if (kt + 1 < nk) stage(cur ^ 1, kt + 1);
    const u16* bA = &lds[cur * BUF];
    bf16x8 aH[4], bH[4];
#pragma unroll
    for (int mi = 0; mi < 4; ++mi) aH[mi] = rdfrag(bA, wr * 64 + mi * 16 + la, g);
#pragma unroll
    for (int ni = 0; ni < 4; ++ni) bH[ni] = rdfrag(bA + 4096, wc * 64 + ni * 16 + la, g);
#pragma unroll
    for (int mi = 0; mi < 4; ++mi)
#pragma unroll
      for (int ni = 0; ni < 4; ++ni)
        acc[mi][ni] = mfma16(aH[mi], bH[ni], acc[mi][ni]);
    __syncthreads();
    cur ^= 1;
  }

#pragma unroll
  for (int mi = 0; mi < 4; ++mi) {
    const int mbase = m0 + wr * 64 + mi * 16 + g * 4;
#pragma unroll
    for (int ni = 0; ni < 4; ++ni) {
      const int n = n0 + wc * 64 + ni * 16 + la;
      const float bv_ = bias[n];
#pragma unroll
      for (int r = 0; r < 4; ++r)
        Cf[(size_t)(mbase + r) * N + n] = acc[mi][ni][r] + bv_;
    }
  }
}

// ---------------------------------------------------------------- flash attention
// R12 math/layout; 3 LDS buffers (48KB, 3 blocks/CU); cross-tile pipeline:
// per iter [sync] -> stage(t+2) -> QK-half(t+1) interleaved with softmax+PV(t).
// QK(t+1) is independent of softmax(t) -> compiler can overlap MFMA with VALU.
// XCD-stream swizzle: xcd = B&7 owns 3 complete bh KV streams (L2-resident).
__global__ __launch_bounds__(256, 3) void flash_attn(
    const u16* __restrict__ Q, const u16* __restrict__ Kt,
    const u16* __restrict__ Vt, u16* __restrict__ ctx) {
  __shared__ __align__(16) u16 lds[3 * 8192];
  const int tid = threadIdx.x, lane = tid & 63, w = tid >> 6;
  const int l5 = lane & 31, hi = lane >> 5;
  const int B = blockIdx.x;
  const int xcd = B & 7, idx = B >> 3;       // idx in [0,96)
  const int bh = xcd * 3 + (idx >> 5);       // 3 streams per XCD
  const int b = bh / 12, h = bh % 12;
  const int q0 = (idx & 31) * 128 + w * 32;
  const size_t kbase = (size_t)bh * 4096 * 64;
  const size_t vbase = (size_t)bh * 64 * 4096;

  bf16x8 aQ[4];
#pragma unroll
  for (int ks = 0; ks < 4; ++ks)
    aQ[ks] = ld8(Q + kbase + (size_t)(q0 + l5) * 64 + ks * 16 + hi * 8);

  f32x16 accO0 = {}, accO1 = {}, accLP = {};
  f32x16 M4;
#pragma unroll
  for (int i = 0; i < 16; ++i) M4[i] = -4.0f;
  const u32x4 onebits = {0x3F803F80u, 0x3F803F80u, 0x3F803F80u, 0x3F803F80u};
  const bf16x8 ones = __builtin_bit_cast(bf16x8, onebits);

  int aK0[4], aK1[4];
  {
    const int r0 = l5, f0 = (r0 & 7) ^ (r0 >> 3);
    const int r1 = 32 + l5, f1 = (r1 & 7) ^ (r1 >> 3);
#pragma unroll
    for (int ks = 0; ks < 4; ++ks) {
      aK0[ks] = r0 * 64 + (((ks * 2 + hi) ^ f0) << 3);
      aK1[ks] = r1 * 64 + (((ks * 2 + hi) ^ f1) << 3);
    }
  }

  const u16 *gk0, *gk1, *gv0, *gv1;
  int dK0, dK1, dV0, dV1;
  {
    const int t0 = w * 2, s0_ = t0 * 64 + lane;
    const int sr0 = s0_ >> 3, c0 = (s0_ & 7) ^ ((sr0 & 7) ^ (sr0 >> 3));
    gk0 = Kt + kbase + (size_t)sr0 * 64 + c0 * 8;
    gv0 = Vt + vbase + (size_t)sr0 * 4096 + c0 * 8;
    dK0 = t0 * 512; dV0 = 4096 + t0 * 512;
    const int t1 = t0 + 1, s1_ = t1 * 64 + lane;
    const int sr1 = s1_ >> 3, c1 = (s1_ & 7) ^ ((sr1 & 7) ^ (sr1 >> 3));
    gk1 = Kt + kbase + (size_t)sr1 * 64 + c1 * 8;
    gv1 = Vt + vbase + (size_t)sr1 * 4096 + c1 * 8;
    dK1 = t1 * 512; dV1 = 4096 + t1 * 512;
  }

  auto stage = [&](int bufbase, int tile) {
    gload16(&lds[bufbase + dK0], gk0 + (size_t)tile * 4096);
    gload16(&lds[bufbase + dK1], gk1 + (size_t)tile * 4096);
    gload16(&lds[bufbase + dV0], gv0 + tile * 64);
    gload16(&lds[bufbase + dV1], gv1 + tile * 64);
  };

  // QK for one 32-kv half (half 0: K rows l5 via aK0; half 1: rows 32+l5 via aK1)
  auto qkh = [&](const int B0, const int half) -> f32x16 {
    const int* aK = half ? aK1 : aK0;
    f32x16 s = mfma32(ld8(&lds[B0 + aK[0]]), aQ[0], M4);
#pragma unroll
    for (int ks = 1; ks < 4; ++ks)
      s = mfma32(ld8(&lds[B0 + aK[ks]]), aQ[ks], s);
    return s;
  };

  // softmax + PV for one 32-kv half of tile in buffer B0
  auto smpv = [&](const int B0, const f32x16 sv, const int ct) {
    float p[16];
#pragma unroll
    for (int i = 0; i < 16; ++i) p[i] = __builtin_exp2f(sv[i]);
    u32 W[4][2];
#pragma unroll
    for (int qd = 0; qd < 4; ++qd) {
      W[qd][0] = pk2(p[qd * 4 + 0], p[qd * 4 + 1]);
      W[qd][1] = pk2(p[qd * 4 + 2], p[qd * 4 + 3]);
    }
#pragma unroll
    for (int s2 = 0; s2 < 2; ++s2) {
      i32x2 r1 = __builtin_amdgcn_permlane32_swap((int)W[2 * s2][0], (int)W[2 * s2 + 1][0], false, false);
      i32x2 r2 = __builtin_amdgcn_permlane32_swap((int)W[2 * s2][1], (int)W[2 * s2 + 1][1], false, false);
      u32x4 wq = {(u32)r1.x, (u32)r2.x, (u32)r1.y, (u32)r2.y};
      const bf16x8 pb = __builtin_bit_cast(bf16x8, wq);
      const int ksv = ct * 2 + s2;
      bf16x8 v0 = ld8(&lds[B0 + 4096 + aK0[ksv]]);
      bf16x8 v1 = ld8(&lds[B0 + 4096 + aK1[ksv]]);
      accO0 = mfma32(v0, pb, accO0);
      accO1 = mfma32(v1, pb, accO1);
      accLP = mfma32(ones, pb, accLP);
    }
  };

  stage(0, 0);
  stage(8192, 1);
  __syncthreads();  // drains both prologue stages; tiles 0,1 visible
  f32x16 sA = qkh(0, 0), sB = qkh(0, 1);  // QK(0)

#pragma unroll 1
  for (int t = 0; t < 64; ++t) {
    if (t > 0) __syncthreads();  // drains stage(t+1) [issued iter t-1]; frees buf[(t+2)%3]
    const int bc = (t % 3) * 8192;
    const int bn = ((t + 1) % 3) * 8192;
    const int bs = ((t + 2) % 3) * 8192;
    if (t + 2 < 64) stage(bs, t + 2);
    if (t + 1 < 64) {
      f32x16 nA = qkh(bn, 0);   // independent of smpv(t) -> ILP
      smpv(bc, sA, 0);
      f32x16 nB = qkh(bn, 1);
      smpv(bc, sB, 1);
      sA = nA; sB = nB;
    } else {
      smpv(bc, sA, 0);
      smpv(bc, sB, 1);
    }
  }

  const float inv = __builtin_amdgcn_rcpf(accLP[0]);
  u16* crow = ctx + ((size_t)b * 4096 + q0 + l5) * 768 + h * 64;
#pragma unroll
  for (int dt = 0; dt < 2; ++dt) {
    const f32x16 a = dt ? accO1 : accO0;
#pragma unroll
    for (int rq = 0; rq < 4; ++rq) {
      const int d0 = dt * 32 + 8 * rq + 4 * hi;
      uint2 st;
      st.x = pk2(a[rq * 4 + 0] * inv, a[rq * 4 + 1] * inv);
      st.y = pk2(a[rq * 4 + 2] * inv, a[rq * 4 + 3] * inv);
      *(uint2*)&crow[d0] = st;
    }
  }
}

// ---------------------------------------------------------------- launcher
extern "C" void kernel_launch(void* const* d_in, const int* in_sizes, int n_in,
                              void* d_out, int out_size, void* d_ws, size_t ws_size,
                              hipStream_t stream) {
  constexpr int NQKV = 2 * 4096 * 768;
  constexpr int NW = 768 * 768;
  const float* q = (const float*)d_in[0];
  const float* k = (const float*)d_in[1];
  const float* v = (const float*)d_in[2];
  const float* Wq = (const float*)d_in[3];
  const float* bq = (const float*)d_in[4];
  const float* Wk = (const float*)d_in[5];
  const float* bk = (const float*)d_in[6];
  const float* Wv = (const float*)d_in[7];
  const float* bv = (const float*)d_in[8];
  const float* Wo = (const float*)d_in[9];
  const float* bo = (const float*)d_in[10];

  char* p = (char*)d_ws;
  auto take = [&](size_t n) -> u16* {
    u16* r = (u16*)p;
    p += (n * 2 + 255) & ~(size_t)255;
    return r;
  };
  u16 *wq_h = take(NW), *wk_h = take(NW), *wv_h = take(NW), *wo_h = take(NW);
  u16 *qh = take(NQKV), *kh = take(NQKV), *vt = take(NQKV), *ctx = take(NQKV);

  cvt_hi<<<dim3(288, 4), 256, 0, stream>>>(
      (const float4*)Wq, wq_h, (const float4*)Wk, wk_h,
      (const float4*)Wv, wv_h, (const float4*)Wo, wo_h, NW / 4);

  const float qscale = 0.18033688011112042f;  // log2(e) / sqrt(64)
  gemm_qkv<<<dim3(64, 6, 3), 256, 0, stream>>>(
      q, k, v, wq_h, wk_h, wv_h, bq, bk, bv, qh, kh, vt, qscale);
  flash_attn<<<768, 256, 0, stream>>>(qh, kh, vt, ctx);
  gemm_out<<<dim3(64, 6), 256, 0, stream>>>(ctx, wo_h, bo, (float*)d_out);
}

// Round 15
// 229.358 us; speedup vs baseline: 3.5685x; 3.5685x over previous
//
#include <hip/hip_runtime.h>

// MHA forward: B=2, S=4096, D=768, H=12, Dh=64.  (R12 configuration — best.)
// cvt(weights->bf16) -> gemm_qkv (A fp32-staged, B bf16) -> flash attention
// (swapped QK^T 32x32, KVBLK=64, 4 waves/block, XCD-stream swizzle: each XCD
// owns 3 complete bh KV streams so KV is L2-resident) -> gemm_out.

typedef __attribute__((ext_vector_type(4))) float f32x4;
typedef __attribute__((ext_vector_type(16))) float f32x16;
typedef __attribute__((ext_vector_type(8))) __bf16 bf16x8;
typedef __attribute__((ext_vector_type(2))) int i32x2;
typedef __attribute__((ext_vector_type(4))) unsigned u32x4;
using u16 = unsigned short;
using u32 = unsigned;

__device__ __forceinline__ u16 f2bf(float x) {
  __bf16 h = (__bf16)x;
  return __builtin_bit_cast(u16, h);
}
__device__ __forceinline__ u32 pk2(float lo, float hi) {  // v_cvt_pk_bf16_f32 (RNE)
  u32 r;
  asm("v_cvt_pk_bf16_f32 %0, %1, %2" : "=v"(r) : "v"(lo), "v"(hi));
  return r;
}
__device__ __forceinline__ void gload16(u16* ldsDst, const u16* gSrc) {
  __builtin_amdgcn_global_load_lds(
      (const __attribute__((address_space(1))) void*)gSrc,
      (__attribute__((address_space(3))) void*)ldsDst, 16, 0, 0);
}
__device__ __forceinline__ f32x4 mfma16(bf16x8 a, bf16x8 b, f32x4 c) {
  return __builtin_amdgcn_mfma_f32_16x16x32_bf16(a, b, c, 0, 0, 0);
}
__device__ __forceinline__ f32x16 mfma32(bf16x8 a, bf16x8 b, f32x16 c) {
  return __builtin_amdgcn_mfma_f32_32x32x16_bf16(a, b, c, 0, 0, 0);
}
__device__ __forceinline__ bf16x8 ld8(const u16* p) { return *(const bf16x8*)p; }

// ---------------------------------------------------------------- cvt (weights only)
__global__ void cvt_hi(const float4* __restrict__ in0, u16* o0,
                       const float4* __restrict__ in1, u16* o1,
                       const float4* __restrict__ in2, u16* o2,
                       const float4* __restrict__ in3, u16* o3, int n4) {
  const float4* in = in0; u16* o = o0;
  if (blockIdx.y == 1) { in = in1; o = o1; }
  else if (blockIdx.y == 2) { in = in2; o = o2; }
  else if (blockIdx.y == 3) { in = in3; o = o3; }
  const int stride = gridDim.x * blockDim.x;
  for (int i = blockIdx.x * blockDim.x + threadIdx.x; i < n4; i += stride) {
    float4 x = in[i];
    *(ushort4*)&o[i * 4] = make_ushort4(f2bf(x.x), f2bf(x.y), f2bf(x.z), f2bf(x.w));
  }
}

// ---------------------------------------------------------------- QKV projection GEMM
// C = A * B^T + bias. A:[8192,768] fp32 (staged fp32, cvt on read), B bf16.
__global__ __launch_bounds__(256, 2) void gemm_qkv(
    const float* __restrict__ Aq, const float* __restrict__ Ak,
    const float* __restrict__ Av,
    const u16* __restrict__ wq, const u16* __restrict__ wk, const u16* __restrict__ wv,
    const float* __restrict__ bq, const float* __restrict__ bk,
    const float* __restrict__ bv,
    u16* __restrict__ oq, u16* __restrict__ ok, u16* __restrict__ ov,
    float qscale) {
  constexpr int K = 768;
  constexpr int BUF = 12288;  // u16 units: A 8192 (16KB fp32) | B 4096 (8KB bf16)
  __shared__ __align__(16) u16 lds[2 * BUF];
  const int z = blockIdx.z;
  const float* A = (z == 0) ? Aq : (z == 1) ? Ak : Av;
  const u16* Bh = (z == 0) ? wq : (z == 1) ? wk : wv;
  const float* bias = (z == 0) ? bq : (z == 1) ? bk : bv;
  u16* C = (z == 0) ? oq : (z == 1) ? ok : ov;
  const float scale = (z == 0) ? qscale : 1.f;
  const bool vmode = (z == 2);

  const int tid = threadIdx.x, lane = tid & 63, w = tid >> 6;
  const int wr = w >> 1, wc = w & 1;
  const int g = lane >> 4, la = lane & 15;
  const int m0 = blockIdx.x * 128, n0 = blockIdx.y * 128;

  f32x4 acc[4][4] = {};

  auto stage = [&](int buf, int kt) {
    const int k0 = kt * 32;
    u16* base = &lds[buf * BUF];
#pragma unroll
    for (int j = 0; j < 4; ++j) {
      const int i = w * 4 + j;
      const int r = i * 8 + (lane >> 3);
      const int c = (lane & 7) ^ ((lane >> 3) & 7);
      gload16(base + i * 512, (const u16*)(A + (size_t)(m0 + r) * K + k0 + c * 4));
    }
#pragma unroll
    for (int j = 0; j < 2; ++j) {
      const int t = w * 2 + j;
      const int s = t * 64 + lane;
      const int sr = s >> 3, ph = s & 7, ch = ph ^ (sr & 7);
      const int row = sr * 2 + (ch >> 2), c = ch & 3;
      gload16(base + 8192 + t * 512, Bh + (size_t)(n0 + row) * K + k0 + c * 8);
    }
  };
  auto rdfragA = [&](const float* baseF, int row, int gg) -> bf16x8 {
    const int x = row & 7;
    const f32x4 u = *(const f32x4*)(baseF + row * 32 + (((2 * gg) ^ x) << 2));
    const f32x4 v = *(const f32x4*)(baseF + row * 32 + (((2 * gg + 1) ^ x) << 2));
    u32x4 wq_ = {pk2(u[0], u[1]), pk2(u[2], u[3]), pk2(v[0], v[1]), pk2(v[2], v[3])};
    return __builtin_bit_cast(bf16x8, wq_);
  };
  auto rdfragB = [&](const u16* base, int row, int c) -> bf16x8 {
    const int sr = row >> 1;
    const int ph = (((row & 1) << 2) | c) ^ (sr & 7);
    return ld8(base + sr * 64 + ph * 8);
  };

  stage(0, 0);
  __syncthreads();
  constexpr int nk = K / 32;
  int cur = 0;
  for (int kt = 0; kt < nk; ++kt) {
    if (kt + 1 < nk) stage(cur ^ 1, kt + 1);
    const float* aF = (const float*)&lds[cur * BUF];
    const u16* bB = &lds[cur * BUF + 8192];
    bf16x8 aH[4], bH[4];
#pragma unroll
    for (int ni = 0; ni < 4; ++ni) bH[ni] = rdfragB(bB, wc * 64 + ni * 16 + la, g);
#pragma unroll
    for (int mi = 0; mi < 4; ++mi) aH[mi] = rdfragA(aF, wr * 64 + mi * 16 + la, g);
#pragma unroll
    for (int mi = 0; mi < 4; ++mi)
#pragma unroll
      for (int ni = 0; ni < 4; ++ni)
        acc[mi][ni] = mfma16(aH[mi], bH[ni], acc[mi][ni]);
    __syncthreads();
    cur ^= 1;
  }

#pragma unroll
  for (int mi = 0; mi < 4; ++mi) {
    const int mbase = m0 + wr * 64 + mi * 16 + g * 4;
#pragma unroll
    for (int ni = 0; ni < 4; ++ni) {
      const int n = n0 + wc * 64 + ni * 16 + la;
      const float bv_ = bias[n];
#pragma unroll
      for (int r = 0; r < 4; ++r) {
        const int m = mbase + r;
        const float y = (acc[mi][ni][r] + bv_) * scale;
        const int bb = m >> 12, s = m & 4095, hh = n >> 6, dh = n & 63;
        if (!vmode)
          C[((size_t)(bb * 12 + hh) * 4096 + s) * 64 + dh] = f2bf(y);
        else
          C[((size_t)(bb * 12 + hh) * 64 + dh) * 4096 + s] = f2bf(y);
      }
    }
  }
}

// ---------------------------------------------------------------- out-proj GEMM
__global__ __launch_bounds__(256, 2) void gemm_out(
    const u16* __restrict__ A, const u16* __restrict__ Bh,
    const float* __restrict__ bias, float* __restrict__ Cf) {
  constexpr int K = 768, N = 768;
  constexpr int BUF = 8192;
  __shared__ __align__(16) u16 lds[2 * BUF];
  const int tid = threadIdx.x, lane = tid & 63, w = tid >> 6;
  const int wr = w >> 1, wc = w & 1;
  const int g = lane >> 4, la = lane & 15;
  const int m0 = blockIdx.x * 128, n0 = blockIdx.y * 128;

  f32x4 acc[4][4] = {};

  auto stage = [&](int buf, int kt) {
    const int k0 = kt * 32;
#pragma unroll
    for (int j = 0; j < 2; ++j) {
      const int t = w * 2 + j;
      const int s = t * 64 + lane;
      const int sr = s >> 3, ph = s & 7, ch = ph ^ (sr & 7);
      const int row = sr * 2 + (ch >> 2), c = ch & 3;
      const int gofs = k0 + c * 8;
      u16* base = &lds[buf * BUF];
      gload16(base + t * 512, A + (size_t)(m0 + row) * K + gofs);
      gload16(base + 4096 + t * 512, Bh + (size_t)(n0 + row) * K + gofs);
    }
  };
  auto rdfrag = [&](const u16* base, int row, int c) -> bf16x8 {
    const int sr = row >> 1;
    const int ph = (((row & 1) << 2) | c) ^ (sr & 7);
    return ld8(base + sr * 64 + ph * 8);
  };

  stage(0, 0);
  __syncthreads();
  constexpr int nk = K / 32;
  int cur = 0;
  for (int kt = 0; kt < nk; ++kt) {
    if (kt + 1 < nk) stage(cur ^ 1, kt + 1);
    const u16* bA = &lds[cur * BUF];
    bf16x8 aH[4], bH[4];
#pragma unroll
    for (int mi = 0; mi < 4; ++mi) aH[mi] = rdfrag(bA, wr * 64 + mi * 16 + la, g);
#pragma unroll
    for (int ni = 0; ni < 4; ++ni) bH[ni] = rdfrag(bA + 4096, wc * 64 + ni * 16 + la, g);
#pragma unroll
    for (int mi = 0; mi < 4; ++mi)
#pragma unroll
      for (int ni = 0; ni < 4; ++ni)
        acc[mi][ni] = mfma16(aH[mi], bH[ni], acc[mi][ni]);
    __syncthreads();
    cur ^= 1;
  }

#pragma unroll
  for (int mi = 0; mi < 4; ++mi) {
    const int mbase = m0 + wr * 64 + mi * 16 + g * 4;
#pragma unroll
    for (int ni = 0; ni < 4; ++ni) {
      const int n = n0 + wc * 64 + ni * 16 + la;
      const float bv_ = bias[n];
#pragma unroll
      for (int r = 0; r < 4; ++r)
        Cf[(size_t)(mbase + r) * N + n] = acc[mi][ni][r] + bv_;
    }
  }
}

// ---------------------------------------------------------------- flash attention
// Flat grid 768 with XCD-stream swizzle: xcd = B&7 owns 3 complete bh KV
// streams (3MB, L2-resident), 32 q-tiles each. All 768 blocks co-resident
// (3/CU) -> stage loads are L2 hits. Static max m=4 (exp2 domain); lp via
// ones-MFMA; permlane P redistribution. 84 VGPR + 48 AGPR, no spill.
__global__ __launch_bounds__(256, 3) void flash_attn(
    const u16* __restrict__ Q, const u16* __restrict__ Kt,
    const u16* __restrict__ Vt, u16* __restrict__ ctx) {
  __shared__ __align__(16) u16 lds[2 * 8192];
  const int tid = threadIdx.x, lane = tid & 63, w = tid >> 6;
  const int l5 = lane & 31, hi = lane >> 5;
  const int B = blockIdx.x;
  const int xcd = B & 7, idx = B >> 3;       // idx in [0,96)
  const int bh = xcd * 3 + (idx >> 5);       // 3 streams per XCD
  const int b = bh / 12, h = bh % 12;
  const int q0 = (idx & 31) * 128 + w * 32;
  const size_t kbase = (size_t)bh * 4096 * 64;
  const size_t vbase = (size_t)bh * 64 * 4096;

  bf16x8 aQ[4];
#pragma unroll
  for (int ks = 0; ks < 4; ++ks)
    aQ[ks] = ld8(Q + kbase + (size_t)(q0 + l5) * 64 + ks * 16 + hi * 8);

  f32x16 accO0 = {}, accO1 = {}, accLP = {};
  f32x16 M4;
#pragma unroll
  for (int i = 0; i < 16; ++i) M4[i] = -4.0f;
  const u32x4 onebits = {0x3F803F80u, 0x3F803F80u, 0x3F803F80u, 0x3F803F80u};
  const bf16x8 ones = __builtin_bit_cast(bf16x8, onebits);

  int aK0[4], aK1[4];
  {
    const int r0 = l5, f0 = (r0 & 7) ^ (r0 >> 3);
    const int r1 = 32 + l5, f1 = (r1 & 7) ^ (r1 >> 3);
#pragma unroll
    for (int ks = 0; ks < 4; ++ks) {
      aK0[ks] = r0 * 64 + (((ks * 2 + hi) ^ f0) << 3);
      aK1[ks] = r1 * 64 + (((ks * 2 + hi) ^ f1) << 3);
    }
  }

  const u16 *gk0, *gk1, *gv0, *gv1;
  int dK0, dK1, dV0, dV1;
  {
    const int t0 = w * 2, s0_ = t0 * 64 + lane;
    const int sr0 = s0_ >> 3, c0 = (s0_ & 7) ^ ((sr0 & 7) ^ (sr0 >> 3));
    gk0 = Kt + kbase + (size_t)sr0 * 64 + c0 * 8;
    gv0 = Vt + vbase + (size_t)sr0 * 4096 + c0 * 8;
    dK0 = t0 * 512; dV0 = 4096 + t0 * 512;
    const int t1 = t0 + 1, s1_ = t1 * 64 + lane;
    const int sr1 = s1_ >> 3, c1 = (s1_ & 7) ^ ((sr1 & 7) ^ (sr1 >> 3));
    gk1 = Kt + kbase + (size_t)sr1 * 64 + c1 * 8;
    gv1 = Vt + vbase + (size_t)sr1 * 4096 + c1 * 8;
    dK1 = t1 * 512; dV1 = 4096 + t1 * 512;
  }

  auto stage = [&](int bufbase, int tile) {
    gload16(&lds[bufbase + dK0], gk0 + (size_t)tile * 4096);
    gload16(&lds[bufbase + dK1], gk1 + (size_t)tile * 4096);
    gload16(&lds[bufbase + dV0], gv0 + tile * 64);
    gload16(&lds[bufbase + dV1], gv1 + tile * 64);
  };

  auto body = [&](const int B0) {
    f32x16 s0, s1;
    {
      bf16x8 k0 = ld8(&lds[B0 + aK0[0]]);
      bf16x8 k1 = ld8(&lds[B0 + aK1[0]]);
      s0 = mfma32(k0, aQ[0], M4);
      s1 = mfma32(k1, aQ[0], M4);
    }
#pragma unroll
    for (int ks = 1; ks < 4; ++ks) {
      bf16x8 k0 = ld8(&lds[B0 + aK0[ks]]);
      bf16x8 k1 = ld8(&lds[B0 + aK1[ks]]);
      s0 = mfma32(k0, aQ[ks], s0);
      s1 = mfma32(k1, aQ[ks], s1);
    }
#pragma unroll
    for (int ct = 0; ct < 2; ++ct) {
      const f32x16 sv = ct ? s1 : s0;
      float p[16];
#pragma unroll
      for (int i = 0; i < 16; ++i) p[i] = __builtin_exp2f(sv[i]);
      u32 W[4][2];
#pragma unroll
      for (int qd = 0; qd < 4; ++qd) {
        W[qd][0] = pk2(p[qd * 4 + 0], p[qd * 4 + 1]);
        W[qd][1] = pk2(p[qd * 4 + 2], p[qd * 4 + 3]);
      }
#pragma unroll
      for (int s2 = 0; s2 < 2; ++s2) {
        i32x2 r1 = __builtin_amdgcn_permlane32_swap((int)W[2 * s2][0], (int)W[2 * s2 + 1][0], false, false);
        i32x2 r2 = __builtin_amdgcn_permlane32_swap((int)W[2 * s2][1], (int)W[2 * s2 + 1][1], false, false);
        u32x4 wq = {(u32)r1.x, (u32)r2.x, (u32)r1.y, (u32)r2.y};
        const bf16x8 pb = __builtin_bit_cast(bf16x8, wq);
        const int ksv = ct * 2 + s2;
        bf16x8 v0 = ld8(&lds[B0 + 4096 + aK0[ksv]]);
        bf16x8 v1 = ld8(&lds[B0 + 4096 + aK1[ksv]]);
        accO0 = mfma32(v0, pb, accO0);
        accO1 = mfma32(v1, pb, accO1);
        accLP = mfma32(ones, pb, accLP);
      }
    }
  };

  stage(0, 0);
  __syncthreads();
#pragma unroll 1
  for (int t2 = 0; t2 < 32; ++t2) {
    stage(8192, 2 * t2 + 1);
    body(0);
    __syncthreads();
    if (t2 < 31) stage(0, 2 * t2 + 2);
    body(8192);
    __syncthreads();
  }

  const float inv = __builtin_amdgcn_rcpf(accLP[0]);
  u16* crow = ctx + ((size_t)b * 4096 + q0 + l5) * 768 + h * 64;
#pragma unroll
  for (int dt = 0; dt < 2; ++dt) {
    const f32x16 a = dt ? accO1 : accO0;
#pragma unroll
    for (int rq = 0; rq < 4; ++rq) {
      const int d0 = dt * 32 + 8 * rq + 4 * hi;
      uint2 st;
      st.x = pk2(a[rq * 4 + 0] * inv, a[rq * 4 + 1] * inv);
      st.y = pk2(a[rq * 4 + 2] * inv, a[rq * 4 + 3] * inv);
      *(uint2*)&crow[d0] = st;
    }
  }
}

// ---------------------------------------------------------------- launcher
extern "C" void kernel_launch(void* const* d_in, const int* in_sizes, int n_in,
                              void* d_out, int out_size, void* d_ws, size_t ws_size,
                              hipStream_t stream) {
  constexpr int NQKV = 2 * 4096 * 768;
  constexpr int NW = 768 * 768;
  const float* q = (const float*)d_in[0];
  const float* k = (const float*)d_in[1];
  const float* v = (const float*)d_in[2];
  const float* Wq = (const float*)d_in[3];
  const float* bq = (const float*)d_in[4];
  const float* Wk = (const float*)d_in[5];
  const float* bk = (const float*)d_in[6];
  const float* Wv = (const float*)d_in[7];
  const float* bv = (const float*)d_in[8];
  const float* Wo = (const float*)d_in[9];
  const float* bo = (const float*)d_in[10];

  char* p = (char*)d_ws;
  auto take = [&](size_t n) -> u16* {
    u16* r = (u16*)p;
    p += (n * 2 + 255) & ~(size_t)255;
    return r;
  };
  u16 *wq_h = take(NW), *wk_h = take(NW), *wv_h = take(NW), *wo_h = take(NW);
  u16 *qh = take(NQKV), *kh = take(NQKV), *vt = take(NQKV), *ctx = take(NQKV);

  cvt_hi<<<dim3(288, 4), 256, 0, stream>>>(
      (const float4*)Wq, wq_h, (const float4*)Wk, wk_h,
      (const float4*)Wv, wv_h, (const float4*)Wo, wo_h, NW / 4);

  const float qscale = 0.18033688011112042f;  // log2(e) / sqrt(64)
  gemm_qkv<<<dim3(64, 6, 3), 256, 0, stream>>>(
      q, k, v, wq_h, wk_h, wv_h, bq, bk, bv, qh, kh, vt, qscale);
  flash_attn<<<768, 256, 0, stream>>>(qh, kh, vt, ctx);
  gemm_out<<<dim3(64, 6), 256, 0, stream>>>(ctx, wo_h, bo, (float*)d_out);
}